// Round 12
// baseline (314.347 us; speedup 1.0000x reference)
//
#include <hip/hip_runtime.h>

typedef __attribute__((ext_vector_type(4))) float f32x4;

#define NB 16384
#define ND 32
#define NK 128

__host__ __device__ constexpr int rbase(int d) {
  return 8*(d>>2)*((d>>2)+1) + (d&3)*4*((d>>2)+1);
}

// ---------------------------------------------------------------------------
// Kernel 1 (v7: 4-sample barrier periods for HBM duty cycle): per-cluster
// scatter M = sum_b x x^T (lower-tri, rect-packed strips) + column sums S,
// for a 64-k tile and a 64-sample chunk.
// grid = 512 (ktile = bx&1, chunk = bx>>1), block = 256, 2 blocks/CU.
// Per iteration: stage 4 samples (8 b128 loads in flight per wave -> 64KB/CU
// outstanding, covers HBM latency at throttled clock), barrier, compute 4
// samples, barrier.  16 iterations (was 32) -> half the vmcnt(0) drains.
// LDS [4][64][37] floats, stride 37 (odd): staging writes 2-way (free),
// compute row reads (5*kl+j)%32 bijective -> conflict-free (r11 verified).
// Per-block partial layout: [608][64] floats at part + blockIdx*38912.
// Partials stored nontemporal (r8/r10 A/B: NT >= plain).
// ---------------------------------------------------------------------------
template<int SP>
__device__ __forceinline__ void k1_body(const float* __restrict__ x,
                                        float* __restrict__ part,
                                        float* __restrict__ vs,
                                        int k0, int b0, int t) {
  constexpr int CL = 4*(SP+1);   // cols of low strip  R=SP
  constexpr int CH = 4*(8-SP);   // cols of high strip R=7-SP
  constexpr int NV = CH;         // row values used: 0..NV-1
  const int sd = t >> 3, sj = t & 7;   // staging: row d, float4-group
  const int kl = t & 63;               // compute: local k

  float aL[4][CL];
  float aH[4][CH];
  float ssum[8];
  #pragma unroll
  for (int r=0;r<4;r++){
    #pragma unroll
    for (int c=0;c<CL;c++) aL[r][c]=0.f;
    #pragma unroll
    for (int c=0;c<CH;c++) aH[r][c]=0.f;
  }
  #pragma unroll
  for (int i=0;i<8;i++) ssum[i]=0.f;

  const float* srcb = x + ((size_t)b0*ND + sd)*NK + k0 + 4*sj;

  for (int g=0; g<16; ++g) {
    // ---- issue all 8 loads (4 samples x 2 f32x4) -> deep VMEM pipeline
    f32x4 A0s[4], A1s[4];
    #pragma unroll
    for (int s=0;s<4;s++){
      const float* src = srcb + (size_t)(4*g+s)*4096;
      A0s[s] = *(const f32x4*)src;
      A1s[s] = *(const f32x4*)(src+32);
    }
    // ---- LDS writes + column-sum accumulation
    #pragma unroll
    for (int s=0;s<4;s++){
      float* dst = vs + s*2368;
      #pragma unroll
      for (int i=0;i<4;i++){
        dst[(4*sj+i)*37 + sd]    = A0s[s][i];
        dst[(4*sj+32+i)*37 + sd] = A1s[s][i];
        ssum[i]   += A0s[s][i];
        ssum[4+i] += A1s[s][i];
      }
    }
    __syncthreads();
    // ---- compute 4 samples
    #pragma unroll
    for (int s=0;s<4;s++){
      const float* row = vs + s*2368 + kl*37;
      float bv[NV];
      #pragma unroll
      for (int j=0;j<NV;j++) bv[j] = row[j];
      #pragma unroll
      for (int r=0;r<4;r++){
        const float al = bv[4*SP+r];     // v[k][4*SP+r]
        const float ah = bv[NV-4+r];     // v[k][4*(7-SP)+r]
        #pragma unroll
        for (int c=0;c<CL;c++) aL[r][c] += al*bv[c];
        #pragma unroll
        for (int c=0;c<CH;c++) aH[r][c] += ah*bv[c];
      }
    }
    __syncthreads();
  }

  float* pb = part + (size_t)blockIdx.x*38912;
  #pragma unroll
  for (int r=0;r<4;r++){
    #pragma unroll
    for (int c=0;c<CL;c++)
      __builtin_nontemporal_store(aL[r][c], &pb[(8*SP*(SP+1) + r*CL + c)*64 + kl]);
    #pragma unroll
    for (int c=0;c<CH;c++)
      __builtin_nontemporal_store(aH[r][c], &pb[(8*(7-SP)*(8-SP) + r*CH + c)*64 + kl]);
  }
  #pragma unroll
  for (int i=0;i<4;i++){
    __builtin_nontemporal_store(ssum[i],   &pb[(576+sd)*64 + 4*sj + i]);
    __builtin_nontemporal_store(ssum[4+i], &pb[(576+sd)*64 + 32 + 4*sj + i]);
  }
}

__global__ __launch_bounds__(256, 2) void k1_scatter(const float* __restrict__ x,
                                                     float* __restrict__ part) {
  __shared__ float vs[4*2368];   // 4 samples x [64 k][37] (odd stride) = 37.9 KB
  const int t = threadIdx.x;
  const int ktile = blockIdx.x & 1;
  const int chunk = blockIdx.x >> 1;
  const int k0 = ktile*64, b0 = chunk*64;
  switch (t>>6) {  // wave-uniform
    case 0:  k1_body<0>(x, part, vs, k0, b0, t); break;
    case 1:  k1_body<1>(x, part, vs, k0, b0, t); break;
    case 2:  k1_body<2>(x, part, vs, k0, b0, t); break;
    default: k1_body<3>(x, part, vs, k0, b0, t); break;
  }
}

// ---------------------------------------------------------------------------
// Kernel 2a: reduce 128-chunk halves of partials.  grid 608, block 256.
// NT loads (no-allocate hint).  Stride 2*38912 per chunk.
// out sfin[h][608][128]
// ---------------------------------------------------------------------------
__global__ void k2a_reduce(const float* __restrict__ part, float* __restrict__ sfin) {
  const int t = threadIdx.x;
  const int bx = blockIdx.x;
  const int h = bx & 1, ktile = (bx>>1)&1, vg = bx>>2;
  const int vidx = vg*4 + (t>>6);
  const int kl = t & 63;
  const float* p = part + ((size_t)(h*128)*2 + ktile)*38912 + vidx*64 + kl;
  float a0=0.f,a1=0.f,a2=0.f,a3=0.f;
  for (int c=0;c<128;c+=4){
    a0 += __builtin_nontemporal_load(&p[(size_t)(c+0)*77824]);
    a1 += __builtin_nontemporal_load(&p[(size_t)(c+1)*77824]);
    a2 += __builtin_nontemporal_load(&p[(size_t)(c+2)*77824]);
    a3 += __builtin_nontemporal_load(&p[(size_t)(c+3)*77824]);
  }
  sfin[h*77824 + vidx*128 + ktile*64 + kl] = (a0+a1)+(a2+a3);
}

// ---------------------------------------------------------------------------
// Kernel 2b: per-cluster cov assembly + Cholesky.  grid 128, block 256.
// ---------------------------------------------------------------------------
__global__ void k2b_chol(const float* __restrict__ sfin,
                         const float* __restrict__ mu0,
                         const float* __restrict__ L0,
                         const float* __restrict__ n0p,
                         float* __restrict__ lpad,
                         float* __restrict__ nmu) {
  const int k = blockIdx.x;
  const int t = threadIdx.x;
  __shared__ float L0s[32*33];
  __shared__ float Am[32*33];
  __shared__ float xdl[32];
  __shared__ float dinv[32];
  const float n0 = n0p[0];
  const float denom = n0 + (float)NB;

  for (int idx = t; idx < 1024; idx += 256)
    L0s[(idx>>5)*33 + (idx&31)] = L0[k*1024 + idx];
  if (t < 32) {
    const float S  = sfin[(576+t)*128 + k] + sfin[77824 + (576+t)*128 + k];
    const float m0 = mu0[t*128 + k];
    nmu[t*128 + k] = (n0*m0 + S) / denom;          // B*x_mu == S
    xdl[t] = S*(1.0f/NB) - m0;
  }
  __syncthreads();

  const float c1 = n0/denom, c2 = 1.0f/denom;
  const float c3 = n0*(float)NB/(denom*denom);
  for (int idx = t; idx < 1024; idx += 256) {
    const int d = idx>>5, e = idx&31;
    const int dd = d>=e?d:e, ee = d>=e?e:d;
    const int vi = rbase(dd) + ee;
    const float M  = sfin[vi*128 + k]      + sfin[77824 + vi*128 + k];
    const float Sd = sfin[(576+d)*128 + k] + sfin[77824 + (576+d)*128 + k];
    const float Se = sfin[(576+e)*128 + k] + sfin[77824 + (576+e)*128 + k];
    const float C = M - Sd*Se*(1.0f/NB);
    float g = 0.f;
    #pragma unroll 8
    for (int f=0; f<32; f++) g += L0s[d*33+f]*L0s[e*33+f];
    float a = g*c1 + C*c2 + xdl[d]*xdl[e]*c3;
    if (d==e) a += 1.0f;
    Am[d*33+e] = a;
  }
  __syncthreads();

  for (int j=0;j<32;j++){
    float acc = 0.f;
    if (t < 32 && t >= j) {
      acc = Am[t*33+j];
      for (int e=0;e<j;e++) acc -= Am[t*33+e]*Am[j*33+e];
    }
    __syncthreads();
    if (t == j) {
      const float dj = sqrtf(acc);
      Am[j*33+j] = dj;
      dinv[j] = 1.0f/dj;
    }
    __syncthreads();
    if (t < 32 && t > j) Am[t*33+j] = acc*dinv[j];
    __syncthreads();
  }

  if (t < 32) {
    const int d = t;
    int rs = 0;
    for (int e=0;e<d;e++) rs += (e+3)>>2;
    rs *= 4;
    const int rl = ((d+3)>>2)*4;
    float* lp = lpad + k*576;
    for (int e=0;e<rl;e++) lp[rs+e] = (e<d) ? Am[d*33+e] : 0.f;
    lp[544+d] = dinv[d];
  }
}

// ---------------------------------------------------------------------------
// Kernel 3: whitening solve z = L^{-1}(x - mu').  grid 512, block 256.
// Block = 32-k tile x 128 samples; full-128B-line accesses; XCD swizzle pairs
// ktiles (2p,2p+1) on the same XCD; NT output stores.
// ---------------------------------------------------------------------------
__global__ __launch_bounds__(256, 2) void k3_whiten(const float* __restrict__ x,
                                                    const float* __restrict__ lpad,
                                                    const float* __restrict__ nmu,
                                                    float* __restrict__ out) {
  __shared__ float Lw[32*580];   // 32 k-rows, stride 580 (16B-aligned, mod32==4)
  __shared__ float muL[32*32];   // [d][kl]
  const int t = threadIdx.x;
  const int bx = blockIdx.x;     // 0..511
  const int m = (bx >> 3) & 1;
  const int u = ((bx >> 4) << 3) | (bx & 7);   // 0..255
  const int ktile = ((u & 1) << 1) | m;        // 2p + m
  const int chunk = u >> 1;                    // 0..127
  const int k0 = ktile*32;

  {
    const f32x4* src = (const f32x4*)(lpad + (size_t)k0*576);
    #pragma unroll
    for (int q=0;q<18;q++){
      const int idx = t + q*256;        // 4608 f32x4 = 32 rows x 144
      const int row = idx/144, col = idx - row*144;
      *(f32x4*)(&Lw[row*580 + col*4]) = src[idx];
    }
    #pragma unroll
    for (int idx=t; idx<1024; idx+=256)
      muL[idx] = nmu[(idx>>5)*128 + k0 + (idx&31)];
  }
  __syncthreads();

  const int kl = t & 31;
  const int so = t >> 5;          // 0..7 sample slot
  const float* Lrow = &Lw[kl*580];
  const int b0 = chunk*128;

  for (int it=0; it<4; ++it) {
    const int base = b0 + it*32 + so;
    const float* xa = x + (size_t)(base     )*4096 + k0 + kl;
    const float* xb = x + (size_t)(base +  8)*4096 + k0 + kl;
    const float* xc = x + (size_t)(base + 16)*4096 + k0 + kl;
    const float* xd = x + (size_t)(base + 24)*4096 + k0 + kl;
    float vA[32], vB[32], vC[32], vD[32];
    #pragma unroll
    for (int d=0; d<32; ++d) vA[d] = xa[d*128];
    #pragma unroll
    for (int d=0; d<32; ++d) vB[d] = xb[d*128];
    #pragma unroll
    for (int d=0; d<32; ++d) vC[d] = xc[d*128];
    #pragma unroll
    for (int d=0; d<32; ++d) vD[d] = xd[d*128];
    #pragma unroll
    for (int d=0; d<32; ++d) {
      const float m2 = muL[d*32 + kl];
      vA[d] -= m2; vB[d] -= m2; vC[d] -= m2; vD[d] -= m2;
    }
    int rs = 0;
    #pragma unroll
    for (int d=0; d<32; ++d) {
      float sA = vA[d], sB = vB[d], sC = vC[d], sD = vD[d];
      const int nq = (d+3)>>2;
      #pragma unroll
      for (int q=0; q<nq; ++q) {
        const f32x4 Lq = *(const f32x4*)(Lrow + rs + 4*q);
        sA -= Lq[0]*vA[4*q+0] + Lq[1]*vA[4*q+1] + Lq[2]*vA[4*q+2] + Lq[3]*vA[4*q+3];
        sB -= Lq[0]*vB[4*q+0] + Lq[1]*vB[4*q+1] + Lq[2]*vB[4*q+2] + Lq[3]*vB[4*q+3];
        sC -= Lq[0]*vC[4*q+0] + Lq[1]*vC[4*q+1] + Lq[2]*vC[4*q+2] + Lq[3]*vC[4*q+3];
        sD -= Lq[0]*vD[4*q+0] + Lq[1]*vD[4*q+1] + Lq[2]*vD[4*q+2] + Lq[3]*vD[4*q+3];
      }
      const float di = Lrow[544+d];
      vA[d] = sA*di; vB[d] = sB*di; vC[d] = sC*di; vD[d] = sD*di;
      rs += 4*nq;
    }
    float* oa = out + (size_t)(base     )*4096 + k0 + kl;
    float* ob = out + (size_t)(base +  8)*4096 + k0 + kl;
    float* oc = out + (size_t)(base + 16)*4096 + k0 + kl;
    float* od = out + (size_t)(base + 24)*4096 + k0 + kl;
    #pragma unroll
    for (int d=0; d<32; ++d) __builtin_nontemporal_store(vA[d], oa + d*128);
    #pragma unroll
    for (int d=0; d<32; ++d) __builtin_nontemporal_store(vB[d], ob + d*128);
    #pragma unroll
    for (int d=0; d<32; ++d) __builtin_nontemporal_store(vC[d], oc + d*128);
    #pragma unroll
    for (int d=0; d<32; ++d) __builtin_nontemporal_store(vD[d], od + d*128);
  }
}

// ---------------------------------------------------------------------------
extern "C" void kernel_launch(void* const* d_in, const int* in_sizes, int n_in,
                              void* d_out, int out_size, void* d_ws, size_t ws_size,
                              hipStream_t stream) {
  const float* x   = (const float*)d_in[0];
  const float* mu0 = (const float*)d_in[1];
  const float* L0  = (const float*)d_in[2];
  const float* n0  = (const float*)d_in[3];
  float* out  = (float*)d_out;
  float* part = out;                    // [512][608][64] floats (scratch in d_out)
  float* sfin = out + 20971520;         // [2][608][128] floats (scratch in d_out)
  float* lpad = (float*)d_ws;           // [128][576]
  float* nmu  = lpad + 128*576;         // [32][128]

  k1_scatter<<<512, 256, 0, stream>>>(x, part);
  k2a_reduce<<<608, 256, 0, stream>>>(part, sfin);
  k2b_chol  <<<128, 256, 0, stream>>>(sfin, mu0, L0, n0, lpad, nmu);
  k3_whiten <<<512, 256, 0, stream>>>(x, lpad, nmu, out);
}

// Round 13
// 214.772 us; speedup vs baseline: 1.4636x; 1.4636x over previous
//
#include <hip/hip_runtime.h>

typedef __attribute__((ext_vector_type(4))) float f32x4;

#define NB 16384
#define ND 32
#define NK 128

__host__ __device__ constexpr int rbase(int d) {
  return 8*(d>>2)*((d>>2)+1) + (d&3)*4*((d>>2)+1);
}

// ---------------------------------------------------------------------------
// Kernel 1 (v8: XOR-swizzled b128 LDS reads): per-cluster scatter
// M = sum_b x x^T (lower-tri, rect-packed strips) + column sums S,
// for a 64-k tile and a 64-sample chunk.
// grid = 512 (ktile = bx&1, chunk = bx>>1), block = 256, 2 blocks/CU.
// LDS tile [2 samples][64 k][32 d], row stride 32 floats (128B), with 16B
// column-group swizzle: value (k,d) stored at k*32 + 4*((d>>2)^(k&7)) + (d&3).
// Compute thread kl reads group g via ds_read_b128 at kl*32 + 4*(g^(kl&7)):
// 8 lanes/16B-slot x 4 banks = every bank serves exactly 8x4B = the 1KB/instr
// floor -> conflict-free b128 (9 instrs/sample vs 36 scalar b32 in r11 =
// the dominant LDS-issue term halved).  Staging writes land 4-way (cheap).
// 2-sample barrier periods, 32 iterations (r12's 4-sample regressed).
// Per-block partial layout: [608][64] floats at part + blockIdx*38912.
// Partials stored nontemporal (r8/r10 A/B: NT >= plain).
// ---------------------------------------------------------------------------
template<int SP>
__device__ __forceinline__ void k1_body(const float* __restrict__ x,
                                        float* __restrict__ part,
                                        float* __restrict__ vs,
                                        int k0, int b0, int t) {
  constexpr int CL = 4*(SP+1);   // cols of low strip  R=SP
  constexpr int CH = 4*(8-SP);   // cols of high strip R=7-SP
  constexpr int NV = CH;         // d-values used: 0..NV-1
  constexpr int NG = NV/4;       // 16B groups to read
  const int sd = t >> 3, sj = t & 7;   // staging: d-col sd, k-group sj
  const int kl = t & 63;               // compute: local k
  const int k7 = kl & 7;

  float aL[4][CL];
  float aH[4][CH];
  float ssum[8];
  #pragma unroll
  for (int r=0;r<4;r++){
    #pragma unroll
    for (int c=0;c<CL;c++) aL[r][c]=0.f;
    #pragma unroll
    for (int c=0;c<CH;c++) aH[r][c]=0.f;
  }
  #pragma unroll
  for (int i=0;i<8;i++) ssum[i]=0.f;

  const int gs = sd >> 2, os = sd & 3;   // staging swizzle pieces

  for (int g=0; g<32; ++g) {
    // stage 2 samples into swizzled LDS tile
    #pragma unroll
    for (int s=0;s<2;s++){
      const int b = b0 + g*2 + s;
      const float* src = x + ((size_t)b*ND + sd)*NK + k0 + 4*sj;
      const f32x4 A0 = *(const f32x4*)src;
      const f32x4 A1 = *(const f32x4*)(src+32);
      float* dst = vs + s*2048;
      #pragma unroll
      for (int i=0;i<4;i++){
        const int r0 = 4*sj+i;              // local k rows (r1 = r0+32, same &7)
        const int sw = 4*(gs ^ (r0&7)) + os;
        dst[r0*32 + sw]        = A0[i];
        dst[(r0+32)*32 + sw]   = A1[i];
        ssum[i]   += A0[i];
        ssum[4+i] += A1[i];
      }
    }
    __syncthreads();
    #pragma unroll
    for (int s=0;s<2;s++){
      const float* rowp = vs + s*2048 + kl*32;
      float bv[NV];
      #pragma unroll
      for (int q=0;q<NG;q++){
        const f32x4 vq = *(const f32x4*)(rowp + 4*(q ^ k7));
        bv[4*q+0]=vq[0]; bv[4*q+1]=vq[1]; bv[4*q+2]=vq[2]; bv[4*q+3]=vq[3];
      }
      #pragma unroll
      for (int r=0;r<4;r++){
        const float al = bv[4*SP+r];     // v[k][4*SP+r]
        const float ah = bv[NV-4+r];     // v[k][4*(7-SP)+r]
        #pragma unroll
        for (int c=0;c<CL;c++) aL[r][c] += al*bv[c];
        #pragma unroll
        for (int c=0;c<CH;c++) aH[r][c] += ah*bv[c];
      }
    }
    __syncthreads();
  }

  float* pb = part + (size_t)blockIdx.x*38912;
  #pragma unroll
  for (int r=0;r<4;r++){
    #pragma unroll
    for (int c=0;c<CL;c++)
      __builtin_nontemporal_store(aL[r][c], &pb[(8*SP*(SP+1) + r*CL + c)*64 + kl]);
    #pragma unroll
    for (int c=0;c<CH;c++)
      __builtin_nontemporal_store(aH[r][c], &pb[(8*(7-SP)*(8-SP) + r*CH + c)*64 + kl]);
  }
  #pragma unroll
  for (int i=0;i<4;i++){
    __builtin_nontemporal_store(ssum[i],   &pb[(576+sd)*64 + 4*sj + i]);
    __builtin_nontemporal_store(ssum[4+i], &pb[(576+sd)*64 + 32 + 4*sj + i]);
  }
}

__global__ __launch_bounds__(256, 2) void k1_scatter(const float* __restrict__ x,
                                                     float* __restrict__ part) {
  __shared__ float vs[2*2048];   // 2 samples x [64 k][32 d] swizzled = 16 KB
  const int t = threadIdx.x;
  const int ktile = blockIdx.x & 1;
  const int chunk = blockIdx.x >> 1;
  const int k0 = ktile*64, b0 = chunk*64;
  switch (t>>6) {  // wave-uniform
    case 0:  k1_body<0>(x, part, vs, k0, b0, t); break;
    case 1:  k1_body<1>(x, part, vs, k0, b0, t); break;
    case 2:  k1_body<2>(x, part, vs, k0, b0, t); break;
    default: k1_body<3>(x, part, vs, k0, b0, t); break;
  }
}

// ---------------------------------------------------------------------------
// Kernel 2a: reduce 128-chunk halves of partials.  grid 608, block 256.
// NT loads (no-allocate hint).  Stride 2*38912 per chunk.
// out sfin[h][608][128]
// ---------------------------------------------------------------------------
__global__ void k2a_reduce(const float* __restrict__ part, float* __restrict__ sfin) {
  const int t = threadIdx.x;
  const int bx = blockIdx.x;
  const int h = bx & 1, ktile = (bx>>1)&1, vg = bx>>2;
  const int vidx = vg*4 + (t>>6);
  const int kl = t & 63;
  const float* p = part + ((size_t)(h*128)*2 + ktile)*38912 + vidx*64 + kl;
  float a0=0.f,a1=0.f,a2=0.f,a3=0.f;
  for (int c=0;c<128;c+=4){
    a0 += __builtin_nontemporal_load(&p[(size_t)(c+0)*77824]);
    a1 += __builtin_nontemporal_load(&p[(size_t)(c+1)*77824]);
    a2 += __builtin_nontemporal_load(&p[(size_t)(c+2)*77824]);
    a3 += __builtin_nontemporal_load(&p[(size_t)(c+3)*77824]);
  }
  sfin[h*77824 + vidx*128 + ktile*64 + kl] = (a0+a1)+(a2+a3);
}

// ---------------------------------------------------------------------------
// Kernel 2b: per-cluster cov assembly + Cholesky.  grid 128, block 256.
// ---------------------------------------------------------------------------
__global__ void k2b_chol(const float* __restrict__ sfin,
                         const float* __restrict__ mu0,
                         const float* __restrict__ L0,
                         const float* __restrict__ n0p,
                         float* __restrict__ lpad,
                         float* __restrict__ nmu) {
  const int k = blockIdx.x;
  const int t = threadIdx.x;
  __shared__ float L0s[32*33];
  __shared__ float Am[32*33];
  __shared__ float xdl[32];
  __shared__ float dinv[32];
  const float n0 = n0p[0];
  const float denom = n0 + (float)NB;

  for (int idx = t; idx < 1024; idx += 256)
    L0s[(idx>>5)*33 + (idx&31)] = L0[k*1024 + idx];
  if (t < 32) {
    const float S  = sfin[(576+t)*128 + k] + sfin[77824 + (576+t)*128 + k];
    const float m0 = mu0[t*128 + k];
    nmu[t*128 + k] = (n0*m0 + S) / denom;          // B*x_mu == S
    xdl[t] = S*(1.0f/NB) - m0;
  }
  __syncthreads();

  const float c1 = n0/denom, c2 = 1.0f/denom;
  const float c3 = n0*(float)NB/(denom*denom);
  for (int idx = t; idx < 1024; idx += 256) {
    const int d = idx>>5, e = idx&31;
    const int dd = d>=e?d:e, ee = d>=e?e:d;
    const int vi = rbase(dd) + ee;
    const float M  = sfin[vi*128 + k]      + sfin[77824 + vi*128 + k];
    const float Sd = sfin[(576+d)*128 + k] + sfin[77824 + (576+d)*128 + k];
    const float Se = sfin[(576+e)*128 + k] + sfin[77824 + (576+e)*128 + k];
    const float C = M - Sd*Se*(1.0f/NB);
    float g = 0.f;
    #pragma unroll 8
    for (int f=0; f<32; f++) g += L0s[d*33+f]*L0s[e*33+f];
    float a = g*c1 + C*c2 + xdl[d]*xdl[e]*c3;
    if (d==e) a += 1.0f;
    Am[d*33+e] = a;
  }
  __syncthreads();

  for (int j=0;j<32;j++){
    float acc = 0.f;
    if (t < 32 && t >= j) {
      acc = Am[t*33+j];
      for (int e=0;e<j;e++) acc -= Am[t*33+e]*Am[j*33+e];
    }
    __syncthreads();
    if (t == j) {
      const float dj = sqrtf(acc);
      Am[j*33+j] = dj;
      dinv[j] = 1.0f/dj;
    }
    __syncthreads();
    if (t < 32 && t > j) Am[t*33+j] = acc*dinv[j];
    __syncthreads();
  }

  if (t < 32) {
    const int d = t;
    int rs = 0;
    for (int e=0;e<d;e++) rs += (e+3)>>2;
    rs *= 4;
    const int rl = ((d+3)>>2)*4;
    float* lp = lpad + k*576;
    for (int e=0;e<rl;e++) lp[rs+e] = (e<d) ? Am[d*33+e] : 0.f;
    lp[544+d] = dinv[d];
  }
}

// ---------------------------------------------------------------------------
// Kernel 3: whitening solve z = L^{-1}(x - mu').  grid 512, block 256.
// Block = 32-k tile x 128 samples; full-128B-line accesses; XCD swizzle pairs
// ktiles (2p,2p+1) on the same XCD; NT output stores.
// ---------------------------------------------------------------------------
__global__ __launch_bounds__(256, 2) void k3_whiten(const float* __restrict__ x,
                                                    const float* __restrict__ lpad,
                                                    const float* __restrict__ nmu,
                                                    float* __restrict__ out) {
  __shared__ float Lw[32*580];   // 32 k-rows, stride 580 (16B-aligned, mod32==4)
  __shared__ float muL[32*32];   // [d][kl]
  const int t = threadIdx.x;
  const int bx = blockIdx.x;     // 0..511
  const int m = (bx >> 3) & 1;
  const int u = ((bx >> 4) << 3) | (bx & 7);   // 0..255
  const int ktile = ((u & 1) << 1) | m;        // 2p + m
  const int chunk = u >> 1;                    // 0..127
  const int k0 = ktile*32;

  {
    const f32x4* src = (const f32x4*)(lpad + (size_t)k0*576);
    #pragma unroll
    for (int q=0;q<18;q++){
      const int idx = t + q*256;        // 4608 f32x4 = 32 rows x 144
      const int row = idx/144, col = idx - row*144;
      *(f32x4*)(&Lw[row*580 + col*4]) = src[idx];
    }
    #pragma unroll
    for (int idx=t; idx<1024; idx+=256)
      muL[idx] = nmu[(idx>>5)*128 + k0 + (idx&31)];
  }
  __syncthreads();

  const int kl = t & 31;
  const int so = t >> 5;          // 0..7 sample slot
  const float* Lrow = &Lw[kl*580];
  const int b0 = chunk*128;

  for (int it=0; it<4; ++it) {
    const int base = b0 + it*32 + so;
    const float* xa = x + (size_t)(base     )*4096 + k0 + kl;
    const float* xb = x + (size_t)(base +  8)*4096 + k0 + kl;
    const float* xc = x + (size_t)(base + 16)*4096 + k0 + kl;
    const float* xd = x + (size_t)(base + 24)*4096 + k0 + kl;
    float vA[32], vB[32], vC[32], vD[32];
    #pragma unroll
    for (int d=0; d<32; ++d) vA[d] = xa[d*128];
    #pragma unroll
    for (int d=0; d<32; ++d) vB[d] = xb[d*128];
    #pragma unroll
    for (int d=0; d<32; ++d) vC[d] = xc[d*128];
    #pragma unroll
    for (int d=0; d<32; ++d) vD[d] = xd[d*128];
    #pragma unroll
    for (int d=0; d<32; ++d) {
      const float m2 = muL[d*32 + kl];
      vA[d] -= m2; vB[d] -= m2; vC[d] -= m2; vD[d] -= m2;
    }
    int rs = 0;
    #pragma unroll
    for (int d=0; d<32; ++d) {
      float sA = vA[d], sB = vB[d], sC = vC[d], sD = vD[d];
      const int nq = (d+3)>>2;
      #pragma unroll
      for (int q=0; q<nq; ++q) {
        const f32x4 Lq = *(const f32x4*)(Lrow + rs + 4*q);
        sA -= Lq[0]*vA[4*q+0] + Lq[1]*vA[4*q+1] + Lq[2]*vA[4*q+2] + Lq[3]*vA[4*q+3];
        sB -= Lq[0]*vB[4*q+0] + Lq[1]*vB[4*q+1] + Lq[2]*vB[4*q+2] + Lq[3]*vB[4*q+3];
        sC -= Lq[0]*vC[4*q+0] + Lq[1]*vC[4*q+1] + Lq[2]*vC[4*q+2] + Lq[3]*vC[4*q+3];
        sD -= Lq[0]*vD[4*q+0] + Lq[1]*vD[4*q+1] + Lq[2]*vD[4*q+2] + Lq[3]*vD[4*q+3];
      }
      const float di = Lrow[544+d];
      vA[d] = sA*di; vB[d] = sB*di; vC[d] = sC*di; vD[d] = sD*di;
      rs += 4*nq;
    }
    float* oa = out + (size_t)(base     )*4096 + k0 + kl;
    float* ob = out + (size_t)(base +  8)*4096 + k0 + kl;
    float* oc = out + (size_t)(base + 16)*4096 + k0 + kl;
    float* od = out + (size_t)(base + 24)*4096 + k0 + kl;
    #pragma unroll
    for (int d=0; d<32; ++d) __builtin_nontemporal_store(vA[d], oa + d*128);
    #pragma unroll
    for (int d=0; d<32; ++d) __builtin_nontemporal_store(vB[d], ob + d*128);
    #pragma unroll
    for (int d=0; d<32; ++d) __builtin_nontemporal_store(vC[d], oc + d*128);
    #pragma unroll
    for (int d=0; d<32; ++d) __builtin_nontemporal_store(vD[d], od + d*128);
  }
}

// ---------------------------------------------------------------------------
extern "C" void kernel_launch(void* const* d_in, const int* in_sizes, int n_in,
                              void* d_out, int out_size, void* d_ws, size_t ws_size,
                              hipStream_t stream) {
  const float* x   = (const float*)d_in[0];
  const float* mu0 = (const float*)d_in[1];
  const float* L0  = (const float*)d_in[2];
  const float* n0  = (const float*)d_in[3];
  float* out  = (float*)d_out;
  float* part = out;                    // [512][608][64] floats (scratch in d_out)
  float* sfin = out + 20971520;         // [2][608][128] floats (scratch in d_out)
  float* lpad = (float*)d_ws;           // [128][576]
  float* nmu  = lpad + 128*576;         // [32][128]

  k1_scatter<<<512, 256, 0, stream>>>(x, part);
  k2a_reduce<<<608, 256, 0, stream>>>(part, sfin);
  k2b_chol  <<<128, 256, 0, stream>>>(sfin, mu0, L0, n0, lpad, nmu);
  k3_whiten <<<512, 256, 0, stream>>>(x, lpad, nmu, out);
}

// Round 14
// 198.716 us; speedup vs baseline: 1.5819x; 1.0808x over previous
//
#include <hip/hip_runtime.h>

typedef __attribute__((ext_vector_type(4))) float f32x4;
typedef __attribute__((ext_vector_type(8))) short short8;

#define NB 16384
#define ND 32
#define NK 128

// RTNE float->bf16 (inputs are finite randn; no NaN path needed)
__device__ __forceinline__ unsigned bfbits(float f){
  union { float f; unsigned u; } v; v.f = f;
  const unsigned u = v.u;
  return (u + 0x7FFFu + ((u>>16)&1u)) >> 16;
}
__device__ __forceinline__ unsigned pkbf(float lo, float hi){
  return bfbits(lo) | (bfbits(hi) << 16);
}

// ---------------------------------------------------------------------------
// Kernel 1 (v9, MFMA): per-cluster scatter M_k = X_k X_k^T (FULL 32x32) and
// column sums S via bf16 MFMA 16x16x32.  The 144-FMA/sample scalar wall (which
// is clock-throttled ~2x under dense load, r2-vs-r10 A/B) becomes ~2us of
// matrix pipe; k1 is then a pure HBM stream (clock-insensitive).
// grid = 256 (ktile = bx&3 -> 32 k, cb = bx>>2 -> 256 samples), block = 512.
// Per 32-sample chunk: stage x -> LDS bf16 [32 k][32 d][16 sample-pair u32]
// (64 KB); each wave owns 4 clusters; per cluster 2 ds_read_b128 fragments
// (rows 0-15 / 16-31) serve BOTH MFMA operands (D = X X^T: B-frag == A-frag,
// the guide's verified A*B^T pattern) -> 4 MFMA tiles + 2 ones-MFMA for S.
// Frag reads: word = d*16 + (l>>4)*4 -> exactly 8 words/bank = conflict-free
// b128 floor.  Staging writes rotated by kq (sp = shalf*8 + (p+kq)&7) -> 4-way.
// Each 128B k-line (32 floats) is consumed by exactly ONE block -> clean fetch.
// Partials: part[cb][k][1056] (1024 M + 32 S), PLAIN stores (L2/L3-resident,
// 34.6 MB total; k2a reads them from L3).
// bf16 precision: cov perturbation ~1e-4 vs +1.0 eye regularization -> ok.
// ---------------------------------------------------------------------------
__global__ __launch_bounds__(512, 2) void k1_scatter(const float* __restrict__ x,
                                                     float* __restrict__ part) {
  __shared__ float vs[16384];        // 32 clusters x 512 u32 = 64 KB
  const int t = threadIdx.x;
  const int bx = blockIdx.x;         // 0..255
  const int ktile = bx & 3;
  const int cb = bx >> 2;            // 0..63
  const int k0 = ktile*32;

  // staging decomposition: t -> (shalf, d, kq)
  const int shalf = t >> 8;          // 0..1  (which 16-sample half)
  const int d     = (t >> 3) & 31;   // 0..31
  const int kq    = t & 7;           // k-quad 0..7 (4 clusters each)
  const float* xb = x + (size_t)d*128 + k0 + 4*kq;

  // compute decomposition: lane l, wave w
  const int l = t & 63;
  const int w = t >> 6;              // 0..7

  f32x4 acc[4][4];                   // [cluster][tile i*2+j]
  f32x4 accS[4][2];                  // [cluster][M-tile]
  #pragma unroll
  for (int c=0;c<4;c++){
    #pragma unroll
    for (int q=0;q<4;q++){ acc[c][q][0]=0.f; acc[c][q][1]=0.f; acc[c][q][2]=0.f; acc[c][q][3]=0.f; }
    #pragma unroll
    for (int q=0;q<2;q++){ accS[c][q][0]=0.f; accS[c][q][1]=0.f; accS[c][q][2]=0.f; accS[c][q][3]=0.f; }
  }

  const short8 ones = {0x3F80,0x3F80,0x3F80,0x3F80,0x3F80,0x3F80,0x3F80,0x3F80};
  unsigned* vsw = (unsigned*)vs;

  for (int ch = 0; ch < 8; ++ch) {
    const int sb = cb*256 + ch*32 + shalf*16;
    // ---- issue all 16 global loads (8 sample-pairs x 2) -> deep VMEM pipe
    f32x4 La[8], Lb[8];
    #pragma unroll
    for (int p = 0; p < 8; ++p) {
      const int pr = (p + kq) & 7;               // rotation: spreads LDS banks
      const float* src = xb + (size_t)(sb + 2*pr)*4096;
      La[p] = *(const f32x4*)src;
      Lb[p] = *(const f32x4*)(src + 4096);
    }
    // ---- pack bf16 pairs + LDS writes  [k=4kq+i][d][sp]
    #pragma unroll
    for (int p = 0; p < 8; ++p) {
      const int pr = (p + kq) & 7;
      const int sp = shalf*8 + pr;
      #pragma unroll
      for (int i = 0; i < 4; ++i)
        vsw[(4*kq + i)*512 + d*16 + sp] = pkbf(La[p][i], Lb[p][i]);
    }
    __syncthreads();
    // ---- MFMA: 4 clusters per wave
    #pragma unroll
    for (int c = 0; c < 4; ++c) {
      const int kk = w*4 + c;
      const float* base = vs + kk*512;
      const short8 f0 = *(const short8*)(base + (l&15)*16      + (l>>4)*4);
      const short8 f1 = *(const short8*)(base + (l&15)*16 + 256 + (l>>4)*4);
      acc[c][0]  = __builtin_amdgcn_mfma_f32_16x16x32_bf16(f0, f0, acc[c][0], 0,0,0);
      acc[c][1]  = __builtin_amdgcn_mfma_f32_16x16x32_bf16(f0, f1, acc[c][1], 0,0,0);
      acc[c][2]  = __builtin_amdgcn_mfma_f32_16x16x32_bf16(f1, f0, acc[c][2], 0,0,0);
      acc[c][3]  = __builtin_amdgcn_mfma_f32_16x16x32_bf16(f1, f1, acc[c][3], 0,0,0);
      accS[c][0] = __builtin_amdgcn_mfma_f32_16x16x32_bf16(f0, ones, accS[c][0], 0,0,0);
      accS[c][1] = __builtin_amdgcn_mfma_f32_16x16x32_bf16(f1, ones, accS[c][1], 0,0,0);
    }
    __syncthreads();
  }

  // ---- epilogue: C/D layout col = l&15, row = (l>>4)*4 + reg (m89-verified)
  const int col = l & 15, rw = (l >> 4) * 4;
  #pragma unroll
  for (int c = 0; c < 4; ++c) {
    const int kg = k0 + w*4 + c;
    float* pb = part + ((size_t)cb*128 + kg)*1056;
    #pragma unroll
    for (int i = 0; i < 2; ++i)
      #pragma unroll
      for (int j = 0; j < 2; ++j)
        #pragma unroll
        for (int r = 0; r < 4; ++r)
          pb[(i*16 + rw + r)*32 + j*16 + col] = acc[c][i*2+j][r];
    if (col == 0) {
      #pragma unroll
      for (int i = 0; i < 2; ++i)
        #pragma unroll
        for (int r = 0; r < 4; ++r)
          pb[1024 + i*16 + rw + r] = accS[c][i][r];
    }
  }
}

// ---------------------------------------------------------------------------
// Kernel 2a: reduce partials over 64 chunk-blocks.  grid 528 x 256.
// part[cb][135168], contiguous outputs -> fully coalesced; partials are
// L3-resident (34.6 MB), plain loads.
// out sfin[135168] = [128 k][1056]
// ---------------------------------------------------------------------------
__global__ void k2a_reduce(const float* __restrict__ part, float* __restrict__ sfin) {
  const size_t idx = (size_t)blockIdx.x*256 + threadIdx.x;   // 0..135167
  const float* p = part + idx;
  float a0=0.f,a1=0.f,a2=0.f,a3=0.f;
  for (int c = 0; c < 64; c += 4) {
    a0 += p[(size_t)(c+0)*135168];
    a1 += p[(size_t)(c+1)*135168];
    a2 += p[(size_t)(c+2)*135168];
    a3 += p[(size_t)(c+3)*135168];
  }
  sfin[idx] = (a0+a1)+(a2+a3);
}

// ---------------------------------------------------------------------------
// Kernel 2b: per-cluster cov assembly + Cholesky.  grid 128, block 256.
// sfin[k][1056]: M (full 32x32) at d*32+e, S at 1024+d.
// ---------------------------------------------------------------------------
__global__ void k2b_chol(const float* __restrict__ sfin,
                         const float* __restrict__ mu0,
                         const float* __restrict__ L0,
                         const float* __restrict__ n0p,
                         float* __restrict__ lpad,
                         float* __restrict__ nmu) {
  const int k = blockIdx.x;
  const int t = threadIdx.x;
  __shared__ float L0s[32*33];
  __shared__ float Am[32*33];
  __shared__ float xdl[32];
  __shared__ float dinv[32];
  const float n0 = n0p[0];
  const float denom = n0 + (float)NB;
  const float* sk = sfin + (size_t)k*1056;

  for (int idx = t; idx < 1024; idx += 256)
    L0s[(idx>>5)*33 + (idx&31)] = L0[k*1024 + idx];
  if (t < 32) {
    const float S  = sk[1024 + t];
    const float m0 = mu0[t*128 + k];
    nmu[t*128 + k] = (n0*m0 + S) / denom;          // B*x_mu == S
    xdl[t] = S*(1.0f/NB) - m0;
  }
  __syncthreads();

  const float c1 = n0/denom, c2 = 1.0f/denom;
  const float c3 = n0*(float)NB/(denom*denom);
  for (int idx = t; idx < 1024; idx += 256) {
    const int d = idx>>5, e = idx&31;
    const float M  = sk[d*32 + e];
    const float Sd = sk[1024 + d];
    const float Se = sk[1024 + e];
    const float C = M - Sd*Se*(1.0f/NB);
    float g = 0.f;
    #pragma unroll 8
    for (int f=0; f<32; f++) g += L0s[d*33+f]*L0s[e*33+f];
    float a = g*c1 + C*c2 + xdl[d]*xdl[e]*c3;
    if (d==e) a += 1.0f;
    Am[d*33+e] = a;
  }
  __syncthreads();

  for (int j=0;j<32;j++){
    float acc = 0.f;
    if (t < 32 && t >= j) {
      acc = Am[t*33+j];
      for (int e=0;e<j;e++) acc -= Am[t*33+e]*Am[j*33+e];
    }
    __syncthreads();
    if (t == j) {
      const float dj = sqrtf(acc);
      Am[j*33+j] = dj;
      dinv[j] = 1.0f/dj;
    }
    __syncthreads();
    if (t < 32 && t > j) Am[t*33+j] = acc*dinv[j];
    __syncthreads();
  }

  if (t < 32) {
    const int d = t;
    int rs = 0;
    for (int e=0;e<d;e++) rs += (e+3)>>2;
    rs *= 4;
    const int rl = ((d+3)>>2)*4;
    float* lp = lpad + k*576;
    for (int e=0;e<rl;e++) lp[rs+e] = (e<d) ? Am[d*33+e] : 0.f;
    lp[544+d] = dinv[d];
  }
}

// ---------------------------------------------------------------------------
// Kernel 3 (frozen since r4, ~72us at HBM roofline): whitening solve
// z = L^{-1}(x - mu').  grid 512, block 256.  Full-128B-line accesses;
// XCD swizzle pairs ktiles (2p,2p+1) on the same XCD; NT output stores.
// ---------------------------------------------------------------------------
__global__ __launch_bounds__(256, 2) void k3_whiten(const float* __restrict__ x,
                                                    const float* __restrict__ lpad,
                                                    const float* __restrict__ nmu,
                                                    float* __restrict__ out) {
  __shared__ float Lw[32*580];   // 32 k-rows, stride 580 (16B-aligned, mod32==4)
  __shared__ float muL[32*32];   // [d][kl]
  const int t = threadIdx.x;
  const int bx = blockIdx.x;     // 0..511
  const int m = (bx >> 3) & 1;
  const int u = ((bx >> 4) << 3) | (bx & 7);   // 0..255
  const int ktile = ((u & 1) << 1) | m;        // 2p + m
  const int chunk = u >> 1;                    // 0..127
  const int k0 = ktile*32;

  {
    const f32x4* src = (const f32x4*)(lpad + (size_t)k0*576);
    #pragma unroll
    for (int q=0;q<18;q++){
      const int idx = t + q*256;        // 4608 f32x4 = 32 rows x 144
      const int row = idx/144, col = idx - row*144;
      *(f32x4*)(&Lw[row*580 + col*4]) = src[idx];
    }
    #pragma unroll
    for (int idx=t; idx<1024; idx+=256)
      muL[idx] = nmu[(idx>>5)*128 + k0 + (idx&31)];
  }
  __syncthreads();

  const int kl = t & 31;
  const int so = t >> 5;          // 0..7 sample slot
  const float* Lrow = &Lw[kl*580];
  const int b0 = chunk*128;

  for (int it=0; it<4; ++it) {
    const int base = b0 + it*32 + so;
    const float* xa = x + (size_t)(base     )*4096 + k0 + kl;
    const float* xb = x + (size_t)(base +  8)*4096 + k0 + kl;
    const float* xc = x + (size_t)(base + 16)*4096 + k0 + kl;
    const float* xd = x + (size_t)(base + 24)*4096 + k0 + kl;
    float vA[32], vB[32], vC[32], vD[32];
    #pragma unroll
    for (int d=0; d<32; ++d) vA[d] = xa[d*128];
    #pragma unroll
    for (int d=0; d<32; ++d) vB[d] = xb[d*128];
    #pragma unroll
    for (int d=0; d<32; ++d) vC[d] = xc[d*128];
    #pragma unroll
    for (int d=0; d<32; ++d) vD[d] = xd[d*128];
    #pragma unroll
    for (int d=0; d<32; ++d) {
      const float m2 = muL[d*32 + kl];
      vA[d] -= m2; vB[d] -= m2; vC[d] -= m2; vD[d] -= m2;
    }
    int rs = 0;
    #pragma unroll
    for (int d=0; d<32; ++d) {
      float sA = vA[d], sB = vB[d], sC = vC[d], sD = vD[d];
      const int nq = (d+3)>>2;
      #pragma unroll
      for (int q=0; q<nq; ++q) {
        const f32x4 Lq = *(const f32x4*)(Lrow + rs + 4*q);
        sA -= Lq[0]*vA[4*q+0] + Lq[1]*vA[4*q+1] + Lq[2]*vA[4*q+2] + Lq[3]*vA[4*q+3];
        sB -= Lq[0]*vB[4*q+0] + Lq[1]*vB[4*q+1] + Lq[2]*vB[4*q+2] + Lq[3]*vB[4*q+3];
        sC -= Lq[0]*vC[4*q+0] + Lq[1]*vC[4*q+1] + Lq[2]*vC[4*q+2] + Lq[3]*vC[4*q+3];
        sD -= Lq[0]*vD[4*q+0] + Lq[1]*vD[4*q+1] + Lq[2]*vD[4*q+2] + Lq[3]*vD[4*q+3];
      }
      const float di = Lrow[544+d];
      vA[d] = sA*di; vB[d] = sB*di; vC[d] = sC*di; vD[d] = sD*di;
      rs += 4*nq;
    }
    float* oa = out + (size_t)(base     )*4096 + k0 + kl;
    float* ob = out + (size_t)(base +  8)*4096 + k0 + kl;
    float* oc = out + (size_t)(base + 16)*4096 + k0 + kl;
    float* od = out + (size_t)(base + 24)*4096 + k0 + kl;
    #pragma unroll
    for (int d=0; d<32; ++d) __builtin_nontemporal_store(vA[d], oa + d*128);
    #pragma unroll
    for (int d=0; d<32; ++d) __builtin_nontemporal_store(vB[d], ob + d*128);
    #pragma unroll
    for (int d=0; d<32; ++d) __builtin_nontemporal_store(vC[d], oc + d*128);
    #pragma unroll
    for (int d=0; d<32; ++d) __builtin_nontemporal_store(vD[d], od + d*128);
  }
}

// ---------------------------------------------------------------------------
extern "C" void kernel_launch(void* const* d_in, const int* in_sizes, int n_in,
                              void* d_out, int out_size, void* d_ws, size_t ws_size,
                              hipStream_t stream) {
  const float* x   = (const float*)d_in[0];
  const float* mu0 = (const float*)d_in[1];
  const float* L0  = (const float*)d_in[2];
  const float* n0  = (const float*)d_in[3];
  float* out  = (float*)d_out;
  float* part = out;                    // [64][128][1056] = 8,650,752 floats (scratch in d_out)
  float* sfin = out + 8650752;          // [128][1056]     =   135,168 floats (scratch in d_out)
  float* lpad = (float*)d_ws;           // [128][576]
  float* nmu  = lpad + 128*576;         // [32][128]

  k1_scatter<<<256, 512, 0, stream>>>(x, part);
  k2a_reduce<<<528, 256, 0, stream>>>(part, sfin);
  k2b_chol  <<<128, 256, 0, stream>>>(sfin, mu0, L0, n0, lpad, nmu);
  k3_whiten <<<512, 256, 0, stream>>>(x, lpad, nmu, out);
}